// Round 2
// baseline (227.347 us; speedup 1.0000x reference)
//
#include <hip/hip_runtime.h>

typedef __attribute__((ext_vector_type(8))) short short8;
typedef __attribute__((ext_vector_type(4))) float float4v;

#define BATCH 16
#define CDIM 2048
#define LDIM 64
#define BSTRIDE (CDIM * LDIM) /* 131072 elems per batch */

#define EPITCH 40 /* ushort pitch of Elds rows */
#define DPITCH 33 /* float pitch of Dinv rows */

__device__ __forceinline__ float bf2f(unsigned short u) {
    unsigned int x = ((unsigned int)u) << 16;
    return __uint_as_float(x);
}
__device__ __forceinline__ unsigned short f2bf(float f) {
    unsigned int x = __float_as_uint(f);
    x += 0x7fffu + ((x >> 16) & 1u); // RNE
    return (unsigned short)(x >> 16);
}

// ---- Fused prepass (one launch): zero out, q*0.125 -> bf16, transpose k,v -> bf16 ----
// grid = 4 * 2048 blocks x 256 threads; section = blockIdx.x >> 11 (uniform per block).
__global__ __launch_bounds__(256) void prepass_kernel(
    const float* __restrict__ q, const float* __restrict__ k, const float* __restrict__ v,
    float* __restrict__ out, unsigned short* __restrict__ qb,
    unsigned short* __restrict__ kT, unsigned short* __restrict__ vT)
{
    __shared__ float tile[32][33];
    const int sec = blockIdx.x >> 11;
    const int idx = blockIdx.x & 2047;
    const int tid = threadIdx.x;

    if (sec == 0) {
        ((float4v*)out)[idx * 256 + tid] = (float4v){0.f, 0.f, 0.f, 0.f};
    } else if (sec == 1) {
        int i = idx * 256 + tid;
        float4v x = ((const float4v*)q)[i];
        ushort4 o;
        o.x = f2bf(x[0] * 0.125f); o.y = f2bf(x[1] * 0.125f);
        o.z = f2bf(x[2] * 0.125f); o.w = f2bf(x[3] * 0.125f);
        ((ushort4*)qb)[i] = o;
    } else {
        const float* src; unsigned short* dst; int R, C, c0, r0;
        int b = idx >> 7, t = idx & 127;
        if (sec == 2) { R = 64;   C = 2048; c0 = (t >> 1) * 32; r0 = (t & 1) * 32; src = k; dst = kT; }
        else          { R = 2048; C = 64;   c0 = (t & 1) * 32;  r0 = (t >> 1) * 32; src = v; dst = vT; }
        src += (size_t)b * R * C;
        dst += (size_t)b * R * C;
        int tx = tid & 31, ty = tid >> 5;
#pragma unroll
        for (int p = 0; p < 4; p++)
            tile[ty + p * 8][tx] = src[(size_t)(r0 + ty + p * 8) * C + c0 + tx];
        __syncthreads();
#pragma unroll
        for (int p = 0; p < 4; p++)
            dst[(size_t)(c0 + ty + p * 8) * R + r0 + tx] = f2bf(tile[tx][ty + p * 8]);
    }
}

// ---- Main fused attention ----
// Grid: 1024 blocks = 128 m-blocks (MT=16) x 8 n-splits (256 cols, 8 steps of NT=32).
// Block: 1024 threads = 16 waves; wave w = batch w. Target: 2 blocks/CU (VGPR<=64).
// Per step: GEMM1 (S^T) -> exp -> E to LDS -> bar -> D-phase (256 thr, all-b sum,
// 1/D to LDS) -> bar -> GEMM2 (P=E/D from own-wave LDS rows + V from global).
__global__ __launch_bounds__(1024, 8) void attn_main_kernel(
    const unsigned short* __restrict__ qb,
    const unsigned short* __restrict__ kT,
    const unsigned short* __restrict__ vT,
    float* __restrict__ out)
{
    __shared__ unsigned short Elds[BATCH * 16 * EPITCH]; // [b][m(16)][pitch 40] : 20.0 KB
    __shared__ float Dinv[16 * DPITCH];                  // [m][pitch 33] 1/D   : 2.1 KB

    const int tid = threadIdx.x;
    const int w = tid >> 6;   // batch
    const int lane = tid & 63;
    const int c = lane & 15;
    const int q = lane >> 4;

    const int mi = blockIdx.x & 127;
    const int nj = blockIdx.x >> 7;
    const int m0 = mi * 16;
    const int nbase = nj * 256;

    const unsigned short* qb_b = qb + w * BSTRIDE;
    const unsigned short* kT_b = kT + w * BSTRIDE;
    const unsigned short* vT_b = vT + w * BSTRIDE;

    // Persistent Q fragments (Q pre-scaled by 1/8): B-operand, lane holds 8 consecutive i.
    short8 Qf[2];
#pragma unroll
    for (int ks = 0; ks < 2; ks++)
        Qf[ks] = *(const short8*)(qb_b + (m0 + c) * LDIM + ks * 32 + q * 8);

    float4v acc[4]; // [jt] : out tile 16m x 64j per wave
#pragma unroll
    for (int jt = 0; jt < 4; jt++) acc[jt] = (float4v){0.f, 0.f, 0.f, 0.f};

    for (int st = 0; st < 8; st++) {
        const int n0 = nbase + st * 32;

        // ---- GEMM1: S^T (rows n, cols m). A = Kt^T from kT[b][n][i], B = Qf. ----
        float4v Cf[2];
#pragma unroll
        for (int nt = 0; nt < 2; nt++) {
            short8 Af0 = *(const short8*)(kT_b + (n0 + nt * 16 + c) * LDIM + q * 8);
            short8 Af1 = *(const short8*)(kT_b + (n0 + nt * 16 + c) * LDIM + 32 + q * 8);
            float4v d = (float4v){0.f, 0.f, 0.f, 0.f};
            d = __builtin_amdgcn_mfma_f32_16x16x32_bf16(Af0, Qf[0], d, 0, 0, 0);
            d = __builtin_amdgcn_mfma_f32_16x16x32_bf16(Af1, Qf[1], d, 0, 0, 0);
            Cf[nt] = d;
        }

        // exp(S) -> bf16 -> Elds[w][m=c][n]  (C-frag: col=c=m, row=q*4+r=n within tile)
#pragma unroll
        for (int nt = 0; nt < 2; nt++) {
            ushort4 e;
            e.x = f2bf(__expf(Cf[nt][0]));
            e.y = f2bf(__expf(Cf[nt][1]));
            e.z = f2bf(__expf(Cf[nt][2]));
            e.w = f2bf(__expf(Cf[nt][3]));
            *(ushort4*)&Elds[(w * 16 + c) * EPITCH + nt * 16 + q * 4] = e;
        }
        __syncthreads(); // E visible to all waves

        // ---- D-phase: 256 threads = 16 m x 16 n-pairs; sum across 16 batches ----
        if (tid < 256) {
            int m = tid >> 4, np = tid & 15;
            float slo = 0.f, shi = 0.f;
#pragma unroll
            for (int b2 = 0; b2 < BATCH; b2++) {
                unsigned int u = *(const unsigned int*)&Elds[(b2 * 16 + m) * EPITCH + np * 2];
                shi += __uint_as_float(u & 0xffff0000u); // odd n (high ushort) is a float directly
                slo += __uint_as_float(u << 16);         // even n
            }
            Dinv[m * DPITCH + np * 2] = 1.f / slo;
            Dinv[m * DPITCH + np * 2 + 1] = 1.f / shi;
        }
        __syncthreads(); // Dinv visible; also fences E reads before next step's writes

        // ---- GEMM2: acc += (E/D) @ V.  A-frag: own-wave LDS row (one b128). ----
        short8 ev = *(const short8*)&Elds[(w * 16 + c) * EPITCH + q * 8];
        float di[8];
#pragma unroll
        for (int t = 0; t < 8; t++) di[t] = Dinv[c * DPITCH + q * 8 + t];
        short8 Pf;
#pragma unroll
        for (int t = 0; t < 8; t++)
            Pf[t] = (short)f2bf(bf2f((unsigned short)ev[t]) * di[t]);
#pragma unroll
        for (int jt = 0; jt < 4; jt++) {
            short8 Vf = *(const short8*)(vT_b + (jt * 16 + c) * CDIM + n0 + q * 8);
            acc[jt] = __builtin_amdgcn_mfma_f32_16x16x32_bf16(Pf, Vf, acc[jt], 0, 0, 0);
        }
    }

    // Epilogue: C/D layout col=c=j, row=q*4+r=m. 8 n-split blocks accumulate via atomics.
#pragma unroll
    for (int jt = 0; jt < 4; jt++)
#pragma unroll
        for (int r = 0; r < 4; r++) {
            int m = m0 + q * 4 + r;
            atomicAdd(&out[(w * CDIM + m) * LDIM + jt * 16 + c], acc[jt][r]);
        }
}

extern "C" void kernel_launch(void* const* d_in, const int* in_sizes, int n_in,
                              void* d_out, int out_size, void* d_ws, size_t ws_size,
                              hipStream_t stream) {
    const float* q = (const float*)d_in[0];
    const float* k = (const float*)d_in[1];
    const float* v = (const float*)d_in[2];
    float* out = (float*)d_out;

    unsigned short* qb = (unsigned short*)d_ws;        // 4 MB bf16 (pre-scaled by 1/8)
    unsigned short* kT = qb + (size_t)BATCH * BSTRIDE; // 4 MB bf16, [b][n][i]
    unsigned short* vT = kT + (size_t)BATCH * BSTRIDE; // 4 MB bf16, [b][j][n]

    prepass_kernel<<<4 * 2048, 256, 0, stream>>>(q, k, v, out, qb, kT, vT);
    attn_main_kernel<<<1024, 1024, 0, stream>>>(qb, kT, vT, out);
}